// Round 11
// baseline (316.384 us; speedup 1.0000x reference)
//
#include <hip/hip_runtime.h>
#include <math.h>

// Problem shape (fixed by reference setup_inputs):
//   images [32][256][64][64] fp32, words [32][32][768] fp32, mask [32][32] bool,
//   W [256][768] fp32, b [256] fp32
//   out0 weighted_words [32][256][64][64], out1 attn_out [32][32][64][64], fp32.
#define B_   32
#define NC_  256
#define HW_  4096
#define MW_  32
#define E_   768
#define NEG_BIG -3.0e38f

typedef float vf4 __attribute__((ext_vector_type(4)));

// Workspace layout (float offsets).
#define PART_OFF   0          // partials: 8 chunks * 32b * 32m * 256c
#define WP_OFF     2097152    // words_p [b][c][m]: 262144 floats
#define WT_OFF     2359296    // W transposed [e][c]: 196608 floats
#define WORDST_OFF 2555904    // words transposed [b][e][m]: 786432 floats

// ---------------------------------------------------------------------------
// Prep: tiled transposes (W -> WT 768x256; words[b] -> wordsT[b] 768x32).
// ---------------------------------------------------------------------------
__global__ __launch_bounds__(256) void prep_kernel(
    const float* __restrict__ W, const float* __restrict__ words,
    float* __restrict__ WT, float* __restrict__ wordsT) {
  const int tid = threadIdx.x;
  const int tx = tid & 31, ty = tid >> 5;
  if (blockIdx.x < 192) {
    __shared__ float t[32][33];
    const int tc = blockIdx.x / 24, te = blockIdx.x % 24;
    const int c0 = tc * 32, e0 = te * 32;
#pragma unroll
    for (int k = 0; k < 4; ++k) {
      const int r = ty + 8 * k;
      t[r][tx] = W[(c0 + r) * E_ + e0 + tx];
    }
    __syncthreads();
#pragma unroll
    for (int k = 0; k < 4; ++k) {
      const int r = ty + 8 * k;
      WT[(e0 + r) * NC_ + c0 + tx] = t[tx][r];
    }
  } else {
    __shared__ float t[32][33];
    const int idx = blockIdx.x - 192;
    const int b = idx / 24, te = idx % 24;
    const int e0 = te * 32;
    const float* wsrc = words + (size_t)b * MW_ * E_;
    float* wdst = wordsT + (size_t)b * E_ * MW_;
#pragma unroll
    for (int k = 0; k < 4; ++k) {
      const int m = ty + 8 * k;
      t[m][tx] = wsrc[m * E_ + e0 + tx];
    }
    __syncthreads();
#pragma unroll
    for (int k = 0; k < 4; ++k) {
      const int e = ty + 8 * k;
      wdst[(e0 + e) * MW_ + tx] = t[tx][e];
    }
  }
}

// ---------------------------------------------------------------------------
// Stage 1a: words_p partials. part[chunk][b][m][c].
// ---------------------------------------------------------------------------
__global__ __launch_bounds__(256) void stage1_partial(
    const float* __restrict__ wordsT, const float* __restrict__ WT,
    float* __restrict__ part) {
  const int c = threadIdx.x;
  const int b = blockIdx.x >> 3;
  const int chunk = blockIdx.x & 7;
  const int e0 = chunk * 96;
  const float* wt = wordsT + (size_t)b * E_ * MW_;
  float acc[32];
#pragma unroll
  for (int m = 0; m < 32; ++m) acc[m] = 0.f;
#pragma unroll 2
  for (int e = e0; e < e0 + 96; ++e) {
    const float wv = WT[(size_t)e * NC_ + c];
    const float* wr = wt + e * MW_;
#pragma unroll
    for (int m = 0; m < 32; ++m) acc[m] = fmaf(wv, wr[m], acc[m]);
  }
  float* pp = part + ((size_t)chunk * 32 + b) * 32 * 256;
#pragma unroll
  for (int m = 0; m < 32; ++m) pp[m * 256 + c] = acc[m];
}

// ---------------------------------------------------------------------------
// Stage 1b: reduce 8 partials + bias -> wp[b][c][m] (m contiguous).
// ---------------------------------------------------------------------------
__global__ __launch_bounds__(256) void stage1_reduce(
    const float* __restrict__ part, const float* __restrict__ bias,
    float* __restrict__ wp) {
  const int idx = blockIdx.x * 256 + threadIdx.x;
  const int c = idx & 255;
  const int m = (idx >> 8) & 31;
  const int b = idx >> 13;
  float s = bias[c];
#pragma unroll
  for (int k = 0; k < 8; ++k)
    s += part[(((size_t)k * 32 + b) * 32 + m) * 256 + c];
  wp[((size_t)b * 256 + c) * 32 + m] = s;
}

// ---------------------------------------------------------------------------
// Stage 2 (R11): SCALAR-OPERAND attention -- m-split score / c-split PV.
// Why: R4/R6/R8/R10 all pinned at 46-58% VALU across wave/px configs.
// Root cause: wave-uniform ds_read_b128 delivers 64x16B=1KB per 16B of
// unique data; at 4px/thread the per-CU LDS return demand (~256 B/cyc)
// saturates the pipe REGARDLESS of wave count. The delivery-efficient
// broadcast path is the SCALAR pipe (s_load -> SGPR, once per wave).
// R0 used it but streamed 32 floats/ch -> ~2-ch SGPR prefetch depth vs
// ~200cy L2 latency -> 21% duty. Fix:
//   - Score m-split: wave w computes m in [8w,8w+8) for ALL 256 ch ->
//     scalar stream 8 floats/ch (s_load_dwordx8) -> ~8-ch prefetch depth.
//     No score exchange (waves own complete m-slices). Images re-read 4x
//     from L1/L2 (waves share px) -- HBM traffic unchanged.
//   - Softmax: cross-wave reduce of per-px max & sum scalars only (4KB
//     bufs), then slice-normalize. out_a stored by owning wave.
//   - a-broadcast: one 32KB conflict-free abuf pass ([mq][px][lane] vf4).
//   - PV c-split: wave owns 64 ch, wr via 2x s_load_dwordx16 (R0-proven;
//     128B/ch at 2-3 ch SGPR depth covers L2 latency under 256-cyc FMA).
//   - readfirstlane(tid>>6) -> wave index provably SGPR -> all wp
//     addresses scalar. 512 blocks x 256 thr = 2 waves/SIMD.
//   - 3 main barriers. LDS 41KB. launch_bounds(256,2): cap 256, live ~185.
// ---------------------------------------------------------------------------
__global__ __launch_bounds__(256, 2) void attention_fused(
    const float* __restrict__ images, const float* __restrict__ wp,
    const void* __restrict__ mask_raw,
    float* __restrict__ out_w, float* __restrict__ out_a) {
  __shared__ vf4 abuf[8][4][64];     // [m-quad][px][lane] 32 KB
  __shared__ float mxbuf[4][4][64];  // [wave][px][lane] 4 KB
  __shared__ float smbuf[4][4][64];  // 4 KB
  __shared__ int is_word;
  const int tid = threadIdx.x;                       // 0..255
  const int lane = tid & 63;
  const int wu = __builtin_amdgcn_readfirstlane(tid >> 6);  // wave 0..3, SGPR
  const int b = blockIdx.x & 31;                     // batch-minor grid
  const int po = ((blockIdx.x >> 5) << 6) + lane;    // vf4 col in [0,1024)
  const vf4* imgb = (const vf4*)(images + (size_t)b * NC_ * HW_);
  const float* wpb = wp + ((size_t)b << 13);         // wp[b][c][m]

  if (tid == 0) is_word = 1;
  __syncthreads();
  // Mask layout probe (first 1024 bytes only: safe for any layout).
  {
    const int* mi = (const int*)mask_raw;
    const int vv = mi[tid];
    if (vv != 0 && vv != 1 && vv != 0x3F800000) is_word = 0;
  }
  __syncthreads();
  unsigned mbits = 0;
  if (is_word) {
    const int* mi = (const int*)mask_raw;
#pragma unroll
    for (int m = 0; m < 32; ++m)
      mbits |= (mi[(b << 5) + m] != 0 ? 1u : 0u) << m;
  } else {
    const unsigned char* mb = (const unsigned char*)mask_raw;
#pragma unroll
    for (int m = 0; m < 32; ++m)
      mbits |= (mb[(b << 5) + m] != 0 ? 1u : 0u) << m;
  }
  const unsigned mb8 = (mbits >> (wu << 3)) & 0xFFu;  // this wave's m-slice

  // ---- score (m-split): s{px}[j] = sum_c img[c][px] * wp[c][8wu+j] ----
  float s0[8], s1[8], s2[8], s3[8];
#pragma unroll
  for (int m = 0; m < 8; ++m) { s0[m] = 0.f; s1[m] = 0.f; s2[m] = 0.f; s3[m] = 0.f; }

  const float* wps = wpb + (wu << 3);  // + c*32 -> 8-float slice, scalar addr

  vf4 cur[16];
#pragma unroll
  for (int j = 0; j < 16; ++j)
    cur[j] = __builtin_nontemporal_load(&imgb[((size_t)j << 10) + po]);

#pragma unroll 1
  for (int c0 = 0; c0 < 256; c0 += 16) {
    vf4 nxt[16];
    if (c0 + 16 < 256) {
#pragma unroll
      for (int j = 0; j < 16; ++j)
        nxt[j] = __builtin_nontemporal_load(&imgb[((size_t)(c0 + 16 + j) << 10) + po]);
    }
#pragma unroll
    for (int j = 0; j < 16; ++j) {
      const float* wr = wps + ((c0 + j) << 5);  // s_load_dwordx8 slice
      const vf4 v = cur[j];
#pragma unroll
      for (int m = 0; m < 8; ++m) {
        s0[m] = fmaf(v.x, wr[m], s0[m]);
        s1[m] = fmaf(v.y, wr[m], s1[m]);
        s2[m] = fmaf(v.z, wr[m], s2[m]);
        s3[m] = fmaf(v.w, wr[m], s3[m]);
      }
    }
#pragma unroll
    for (int j = 0; j < 16; ++j) cur[j] = nxt[j];  // dead on last iter
  }

  // ---- distributed softmax: scale, local masked max over slice ----
  float l0 = NEG_BIG, l1 = NEG_BIG, l2 = NEG_BIG, l3 = NEG_BIG;
#pragma unroll
  for (int m = 0; m < 8; ++m) {
    s0[m] *= 0.0625f; s1[m] *= 0.0625f; s2[m] *= 0.0625f; s3[m] *= 0.0625f;
    if (!((mb8 >> m) & 1u)) {
      l0 = fmaxf(l0, s0[m]); l1 = fmaxf(l1, s1[m]);
      l2 = fmaxf(l2, s2[m]); l3 = fmaxf(l3, s3[m]);
    }
  }
  mxbuf[wu][0][lane] = l0; mxbuf[wu][1][lane] = l1;
  mxbuf[wu][2][lane] = l2; mxbuf[wu][3][lane] = l3;
  __syncthreads();  // B1
  float g0 = mxbuf[0][0][lane], g1 = mxbuf[0][1][lane];
  float g2 = mxbuf[0][2][lane], g3 = mxbuf[0][3][lane];
#pragma unroll
  for (int w2 = 1; w2 < 4; ++w2) {
    g0 = fmaxf(g0, mxbuf[w2][0][lane]); g1 = fmaxf(g1, mxbuf[w2][1][lane]);
    g2 = fmaxf(g2, mxbuf[w2][2][lane]); g3 = fmaxf(g3, mxbuf[w2][3][lane]);
  }
  float t0 = 0.f, t1 = 0.f, t2 = 0.f, t3 = 0.f;
#pragma unroll
  for (int m = 0; m < 8; ++m) {
    const bool msk = (mb8 >> m) & 1u;
    const float e0 = msk ? 0.f : __expf(s0[m] - g0);
    const float e1 = msk ? 0.f : __expf(s1[m] - g1);
    const float e2 = msk ? 0.f : __expf(s2[m] - g2);
    const float e3 = msk ? 0.f : __expf(s3[m] - g3);
    s0[m] = e0; s1[m] = e1; s2[m] = e2; s3[m] = e3;
    t0 += e0; t1 += e1; t2 += e2; t3 += e3;
  }
  smbuf[wu][0][lane] = t0; smbuf[wu][1][lane] = t1;
  smbuf[wu][2][lane] = t2; smbuf[wu][3][lane] = t3;
  __syncthreads();  // B2
  float u0 = smbuf[0][0][lane], u1 = smbuf[0][1][lane];
  float u2 = smbuf[0][2][lane], u3 = smbuf[0][3][lane];
#pragma unroll
  for (int w2 = 1; w2 < 4; ++w2) {
    u0 += smbuf[w2][0][lane]; u1 += smbuf[w2][1][lane];
    u2 += smbuf[w2][2][lane]; u3 += smbuf[w2][3][lane];
  }
  const float i0 = 1.f / u0, i1 = 1.f / u1, i2 = 1.f / u2, i3 = 1.f / u3;
#pragma unroll
  for (int m = 0; m < 8; ++m) {
    s0[m] *= i0; s1[m] *= i1; s2[m] *= i2; s3[m] *= i3;
  }

  // out_a: this wave stores its own 8 m rows
  {
    vf4* oa = (vf4*)out_a;
#pragma unroll
    for (int m = 0; m < 8; ++m) {
      vf4 a; a.x = s0[m]; a.y = s1[m]; a.z = s2[m]; a.w = s3[m];
      __builtin_nontemporal_store(
          a, &oa[(((size_t)(b << 5) + (wu << 3) + m) << 10) + po]);
    }
  }

  // a-broadcast: wave writes its 2 m-quads x 4 px (lane-consecutive vf4)
  {
    vf4 q0, q1;
    q0.x = s0[0]; q0.y = s0[1]; q0.z = s0[2]; q0.w = s0[3];
    q1.x = s0[4]; q1.y = s0[5]; q1.z = s0[6]; q1.w = s0[7];
    abuf[(wu << 1)][0][lane] = q0; abuf[(wu << 1) + 1][0][lane] = q1;
    q0.x = s1[0]; q0.y = s1[1]; q0.z = s1[2]; q0.w = s1[3];
    q1.x = s1[4]; q1.y = s1[5]; q1.z = s1[6]; q1.w = s1[7];
    abuf[(wu << 1)][1][lane] = q0; abuf[(wu << 1) + 1][1][lane] = q1;
    q0.x = s2[0]; q0.y = s2[1]; q0.z = s2[2]; q0.w = s2[3];
    q1.x = s2[4]; q1.y = s2[5]; q1.z = s2[6]; q1.w = s2[7];
    abuf[(wu << 1)][2][lane] = q0; abuf[(wu << 1) + 1][2][lane] = q1;
    q0.x = s3[0]; q0.y = s3[1]; q0.z = s3[2]; q0.w = s3[3];
    q1.x = s3[4]; q1.y = s3[5]; q1.z = s3[6]; q1.w = s3[7];
    abuf[(wu << 1)][3][lane] = q0; abuf[(wu << 1) + 1][3][lane] = q1;
  }
  __syncthreads();  // B3

  // gather full a[32] per px into registers (one-time, conflict-free)
  float a0[32], a1[32], a2[32], a3[32];
#pragma unroll
  for (int mq = 0; mq < 8; ++mq) {
    const vf4 x0 = abuf[mq][0][lane];
    a0[4 * mq] = x0.x; a0[4 * mq + 1] = x0.y; a0[4 * mq + 2] = x0.z; a0[4 * mq + 3] = x0.w;
    const vf4 x1 = abuf[mq][1][lane];
    a1[4 * mq] = x1.x; a1[4 * mq + 1] = x1.y; a1[4 * mq + 2] = x1.z; a1[4 * mq + 3] = x1.w;
    const vf4 x2 = abuf[mq][2][lane];
    a2[4 * mq] = x2.x; a2[4 * mq + 1] = x2.y; a2[4 * mq + 2] = x2.z; a2[4 * mq + 3] = x2.w;
    const vf4 x3 = abuf[mq][3][lane];
    a3[4 * mq] = x3.x; a3[4 * mq + 1] = x3.y; a3[4 * mq + 2] = x3.z; a3[4 * mq + 3] = x3.w;
  }

  // ---- PV (c-split): this wave's 64 channels; wr via s_load_dwordx16 ----
  vf4* ow = (vf4*)out_w;
#pragma unroll 1
  for (int c0 = 0; c0 < 64; c0 += 4) {
#pragma unroll
    for (int j = 0; j < 4; ++j) {
      const int c = (wu << 6) + c0 + j;
      const float* wr = wpb + (c << 5);  // scalar address -> s_load
      float o0 = 0.f, o1 = 0.f, o2 = 0.f, o3 = 0.f;
#pragma unroll
      for (int m = 0; m < 32; ++m) {
        o0 = fmaf(wr[m], a0[m], o0);
        o1 = fmaf(wr[m], a1[m], o1);
        o2 = fmaf(wr[m], a2[m], o2);
        o3 = fmaf(wr[m], a3[m], o3);
      }
      vf4 o; o.x = o0; o.y = o1; o.z = o2; o.w = o3;
      __builtin_nontemporal_store(o, &ow[(((size_t)(b << 8) + c) << 10) + po]);
    }
  }
}

// ---------------------------------------------------------------------------
extern "C" void kernel_launch(void* const* d_in, const int* in_sizes, int n_in,
                              void* d_out, int out_size, void* d_ws, size_t ws_size,
                              hipStream_t stream) {
  const float* images = (const float*)d_in[0];
  const float* words  = (const float*)d_in[1];
  const void*  mask   = d_in[2];
  const float* W      = (const float*)d_in[3];
  const float* bias   = (const float*)d_in[4];

  float* ws     = (float*)d_ws;
  float* part   = ws + PART_OFF;
  float* wp     = ws + WP_OFF;
  float* WT     = ws + WT_OFF;
  float* wordsT = ws + WORDST_OFF;

  float* out_w = (float*)d_out;
  float* out_a = out_w + (size_t)B_ * NC_ * HW_;

  prep_kernel<<<960, 256, 0, stream>>>(W, words, WT, wordsT);
  stage1_partial<<<256, 256, 0, stream>>>(wordsT, WT, part);
  stage1_reduce<<<1024, 256, 0, stream>>>(part, bias, wp);
  attention_fused<<<512, 256, 0, stream>>>(images, wp, mask, out_w, out_a);
}